// Round 9
// baseline (151.436 us; speedup 1.0000x reference)
//
#include <hip/hip_runtime.h>

typedef short  s16x4 __attribute__((ext_vector_type(4)));
typedef short  s16x8 __attribute__((ext_vector_type(8)));
typedef float  f32x4 __attribute__((ext_vector_type(4)));
typedef float  f32x16 __attribute__((ext_vector_type(16)));

__device__ __forceinline__ unsigned short f2b(float f) {
    unsigned u = __float_as_uint(f);
    u = u + 0x7FFFu + ((u >> 16) & 1u);   // RNE
    return (unsigned short)(u >> 16);
}

__device__ __forceinline__ void gload16(const void* g, void* l) {
    __builtin_amdgcn_global_load_lds((const __attribute__((address_space(1))) unsigned*)g,
                                     (__attribute__((address_space(3))) unsigned*)l,
                                     16, 0, 0);
}

// gemm slot swizzle (period 16)
__device__ __forceinline__ int swz(int x) { return (x ^ (x >> 2)) & 3; }
// fconv slot swizzle for 64B/px rows: spreads px-stride-64B across bank halves.
// Hand-checked: per b128 wave-read, every bank serves exactly 8 rows = structural min.
__device__ __forceinline__ int f2s(int o) { return (o >> 1) & 3; }

// ---------- Bv2[(j*32+k)*256 + a*16+b] = sum_c Z2[b,j,c] * Z3[c,k,a]  (bf16) ----------
__global__ __launch_bounds__(256) void v_kernel(const float* __restrict__ Z2,
                                                const float* __restrict__ Z3,
                                                short* __restrict__ Bv2) {
    __shared__ float z3t[8192];   // [c][a][k]
    __shared__ float z2s[256];    // [b][c]
    const int tid = threadIdx.x, j = blockIdx.x;
    for (int t = tid; t < 8192; t += 256) {
        float v = Z3[t];                     // Z3[c,k,a] flat = c*512 + k*16 + a
        int c = t >> 9, k = (t >> 4) & 31, a = t & 15;
        z3t[c * 512 + a * 32 + k] = v;
    }
    z2s[tid] = Z2[(tid >> 4) * 16384 + j * 16 + (tid & 15)];
    __syncthreads();
    const int a = tid >> 4, b = tid & 15;
    float z2r[16];
    #pragma unroll
    for (int c = 0; c < 16; ++c) z2r[c] = z2s[b * 16 + c];
    float s[32];
    #pragma unroll
    for (int k = 0; k < 32; ++k) s[k] = 0.f;
    #pragma unroll
    for (int c = 0; c < 16; ++c) {
        #pragma unroll
        for (int k4 = 0; k4 < 8; ++k4) {
            f32x4 v = *(const f32x4*)&z3t[c * 512 + a * 32 + k4 * 4];
            #pragma unroll
            for (int r = 0; r < 4; ++r) s[k4 * 4 + r] += z2r[c] * v[r];
        }
    }
    #pragma unroll
    for (int k = 0; k < 32; ++k)
        Bv2[(size_t)(j * 32 + k) * 256 + tid] = (short)f2b(s[k]);
}

// ---------- Z1r[i*256 + a*16+b] = Z1[a,i,b]  (bf16) ----------
__global__ __launch_bounds__(256) void z1r_kernel(const float* __restrict__ Z1,
                                                  short* __restrict__ Z1r) {
    __shared__ float z1s[4096];
    const int tid = threadIdx.x, i0 = blockIdx.x * 16;
    #pragma unroll
    for (int a = 0; a < 16; ++a)
        z1s[a * 256 + tid] = Z1[a * 16384 + i0 * 16 + tid];
    __syncthreads();
    #pragma unroll
    for (int il = 0; il < 16; ++il)
        Z1r[(size_t)(i0 + il) * 256 + tid] =
            (short)f2b(z1s[(tid >> 4) * 256 + il * 16 + (tid & 15)]);
}

// ---------- X_nhwc[j][i][k] = sum_ab Bv2[(j*32+k)][ab] * Z1r[i][ab]  (bf16 MFMA) ----------
__global__ __launch_bounds__(256) void gemm_kernel(const short* __restrict__ Bv2,
                                                   const short* __restrict__ Z1r,
                                                   short* __restrict__ X) {
    __shared__ short sA[128 * 32];
    __shared__ short sB[128 * 32];
    const int tid = threadIdx.x;
    const int w = tid >> 6, lane = tid & 63, lane15 = lane & 15, q = lane >> 4;
    const int wm = w >> 1, wn = w & 1;
    const int bid = blockIdx.x;
    const int l = (bid & 7) * 256 + (bid >> 3);      // XCD-chunked swizzle
    const int n0 = (l >> 3) * 128, i0 = (l & 7) * 128;
    const int rs = lane >> 2, sp = lane & 3;
    const int scol = (sp ^ swz(rs)) << 3;
    const int fl = swz(lane15);

    f32x4 acc[4][4];
    #pragma unroll
    for (int a = 0; a < 4; ++a)
        #pragma unroll
        for (int b = 0; b < 4; ++b) acc[a][b] = (f32x4)0;

    for (int kk = 0; kk < 256; kk += 32) {
        gload16(&Bv2[(size_t)(n0 + w * 16 + rs) * 256 + kk + scol],       (char*)sA + w * 1024);
        gload16(&Bv2[(size_t)(n0 + (w + 4) * 16 + rs) * 256 + kk + scol], (char*)sA + (w + 4) * 1024);
        gload16(&Z1r[(size_t)(i0 + w * 16 + rs) * 256 + kk + scol],       (char*)sB + w * 1024);
        gload16(&Z1r[(size_t)(i0 + (w + 4) * 16 + rs) * 256 + kk + scol], (char*)sB + (w + 4) * 1024);
        __syncthreads();
        s16x8 af[4], bf[4];
        #pragma unroll
        for (int fm = 0; fm < 4; ++fm) {
            const int r = wm * 64 + fm * 16 + lane15;
            af[fm] = *(const s16x8*)&sA[r * 32 + ((q ^ fl) << 3)];
        }
        #pragma unroll
        for (int fn = 0; fn < 4; ++fn) {
            const int r = wn * 64 + fn * 16 + lane15;
            bf[fn] = *(const s16x8*)&sB[r * 32 + ((q ^ fl) << 3)];
        }
        #pragma unroll
        for (int fm = 0; fm < 4; ++fm)
            #pragma unroll
            for (int fn = 0; fn < 4; ++fn)
                acc[fm][fn] = __builtin_amdgcn_mfma_f32_16x16x32_bf16(af[fm], bf[fn], acc[fm][fn], 0, 0, 0);
        __syncthreads();
    }

    #pragma unroll
    for (int fm = 0; fm < 4; ++fm) {
        const int nbase = n0 + wm * 64 + fm * 16;
        const int j = nbase >> 5;
        const int k0 = (nbase & 31) + q * 4;
        #pragma unroll
        for (int fn = 0; fn < 4; ++fn) {
            const int i = i0 + wn * 64 + fn * 16 + lane15;
            s16x4 p;
            #pragma unroll
            for (int r = 0; r < 4; ++r) p[r] = (short)f2b(acc[fm][fn][r]);
            *(s16x4*)&X[(size_t)j * 32768 + i * 32 + k0] = p;
        }
    }
}

// ---------- fused conv1+leaky+conv2+leaky, NHWC, producer/consumer, 32x32x16 MFMA ----------
// 512 threads = 8 waves. Tile: 126 out px x 16 rows, grid 9x64.
// Waves 0-3: conv1 (y1 tiles base -1,31,63,95 -> y1 px -1..126 exactly).
// Waves 4-7: conv2 (out tiles base 0,32,64,96; px 126,127 discarded).
// X ring: 4 rows x 130 px (gx = x0-2+ox); y1 ring: 4 rows x 130 px (oy = px+1).
// Per iteration t: stage X row t+1 || conv1 y1 row t-1 || conv2 out row t-3; ONE barrier.
// Ring disjointness: stage slot (t+1)&3 vs conv1-read {t,t+2,t+3}&3; conv1-write y1
// slot (t+3)&3 vs conv2-read {t,t+1,t+2}&3.
#define XWN 130
#define XRN (XWN * 32)          // shorts per ring row (8320 B)
__global__ __launch_bounds__(512) void fconv_kernel(const short* __restrict__ in,
                                                    const float* __restrict__ W1,
                                                    const float* __restrict__ b1,
                                                    const float* __restrict__ W2,
                                                    const float* __restrict__ b2,
                                                    float* __restrict__ out) {
    __shared__ short xr[4 * XRN];   // 33280 B
    __shared__ short yr[4 * XRN];   // 33280 B
    const int tid = threadIdx.x;
    const int w = tid >> 6, lane = tid & 63, r31 = lane & 31, h = lane >> 5;
    const int bx = blockIdx.x, by = blockIdx.y;
    const int x0 = bx * 126, y0 = by * 16;
    const bool isC1 = (w < 4);
    const int tb = isC1 ? (w * 32 - 1) : ((w - 4) * 32);   // y1-tile base (rel px) / out-tile base

    // A-frags for 32x32x16: A[o][c], o = lane&31, c = kh*16 + h*8 + e  (72 VGPR/wave)
    s16x8 aw[9][2];
    {
        const float* Ws = isC1 ? W1 : W2;
        #pragma unroll
        for (int t = 0; t < 9; ++t)
            #pragma unroll
            for (int kh = 0; kh < 2; ++kh) {
                const int c0 = kh * 16 + h * 8;
                s16x8 a;
                #pragma unroll
                for (int e = 0; e < 8; ++e)
                    a[e] = (short)f2b(Ws[(r31 * 32 + c0 + e) * 9 + t]);
                aw[t][kh] = a;
            }
    }
    // bias per C/D reg: o(reg) = (reg&3) + 8*(reg>>2) + 4*h
    f32x4 bb[4];
    {
        const float* bs = isC1 ? b1 : b2;
        #pragma unroll
        for (int g = 0; g < 4; ++g) bb[g] = *(const f32x4*)&bs[g * 8 + h * 4];
    }

    // persistent zeros for x-halo at image edges (stage skips OOB gx).
    // Barrier REQUIRED before any gload16 lands in xr (round-5 race lesson).
    if (bx == 0 || bx == 8) {
        s16x8* p = (s16x8*)xr;
        for (int i = tid; i < 4 * XWN * 4; i += 512) p[i] = (s16x8)0;
        __syncthreads();
    }

    auto stage = [&](int rho) {                      // X image row y0+rho -> slot (rho+4)&3
        const int gy = y0 + rho;
        char* base = (char*)&xr[((rho + 4) & 3) * XRN];
        if ((unsigned)gy < 1024u) {
            // 520 16B-slots over 512 threads (+8-thread tail)
            {
                const int ox = tid >> 2, u = tid & 3;
                const int gx = x0 - 2 + ox;
                if ((unsigned)gx < 1024u)
                    gload16(&in[(size_t)((gy << 10) + gx) * 32 + ((u ^ f2s(ox)) << 3)],
                            base + (w * 64) * 16);
            }
            {
                const int idx = 512 + tid;
                if (idx < XWN * 4) {                 // tid < 8 (wave 0 tail)
                    const int ox = idx >> 2, u = idx & 3;
                    const int gx = x0 - 2 + ox;
                    if ((unsigned)gx < 1024u)
                        gload16(&in[(size_t)((gy << 10) + gx) * 32 + ((u ^ f2s(ox)) << 3)],
                                base + 512 * 16);
                }
            }
        } else {
            s16x8* b8 = (s16x8*)base;
            for (int i = tid; i < XWN * 4; i += 512) b8[i] = (s16x8)0;
        }
    };

    auto conv1_row = [&](int ry) {                   // y1 image row y0+ry -> slot (ry+4)&3
        const int gy1 = y0 + ry;
        const int ysl = ((ry + 4) & 3) * XRN;
        if ((unsigned)gy1 < 1024u) {
            int xs[3];
            #pragma unroll
            for (int dy = 0; dy < 3; ++dy) xs[dy] = ((ry - 1 + dy + 4) & 3) * XRN;
            f32x16 acc = (f32x16)0;
            #pragma unroll
            for (int dy = 0; dy < 3; ++dy)
                #pragma unroll
                for (int dx = 0; dx < 3; ++dx) {
                    const int ox = tb + r31 + dx + 1;          // X offset 0..129
                    const int fo = f2s(ox);
                    #pragma unroll
                    for (int kh = 0; kh < 2; ++kh) {
                        const s16x8 bfr = *(const s16x8*)&xr[xs[dy] + ox * 32 + (((kh * 2 + h) ^ fo) << 3)];
                        acc = __builtin_amdgcn_mfma_f32_32x32x16_bf16(aw[dy * 3 + dx][kh], bfr, acc, 0, 0, 0);
                    }
                }
            const int p = tb + r31;                  // y1 rel px, -1..126
            const int oy = p + 1;                    // LDS offset 0..127
            const int gx1 = x0 + p;
            const bool valid = (unsigned)gx1 < 1024u;    // conv2 zero-pads y1 at image edge
            const int fo = f2s(oy);
            #pragma unroll
            for (int g = 0; g < 4; ++g) {
                s16x4 pk;
                #pragma unroll
                for (int e = 0; e < 4; ++e) {
                    float f = acc[g * 4 + e] + bb[g][e];
                    f = f >= 0.f ? f : 0.01f * f;
                    pk[e] = valid ? (short)f2b(f) : (short)0;
                }
                *(s16x4*)&yr[ysl + oy * 32 + ((g ^ fo) << 3) + h * 4] = pk;
            }
        } else {                                     // conv2 zero-padding row (waves 0-3 only)
            s16x8* b8 = (s16x8*)&yr[ysl];
            for (int i = tid; i < XWN * 4; i += 256) b8[i] = (s16x8)0;
        }
    };

    auto conv2_row = [&](int ro) {                   // out image row y0+ro (always valid)
        const int gy = y0 + ro;
        int ys[3];
        #pragma unroll
        for (int dy = 0; dy < 3; ++dy) ys[dy] = ((ro - 1 + dy + 4) & 3) * XRN;
        f32x16 acc = (f32x16)0;
        #pragma unroll
        for (int dy = 0; dy < 3; ++dy)
            #pragma unroll
            for (int dx = 0; dx < 3; ++dx) {
                const int oy = tb + r31 + dx;                  // y1 offset 0..129
                const int fo = f2s(oy);
                #pragma unroll
                for (int kh = 0; kh < 2; ++kh) {
                    const s16x8 bfr = *(const s16x8*)&yr[ys[dy] + oy * 32 + (((kh * 2 + h) ^ fo) << 3)];
                    acc = __builtin_amdgcn_mfma_f32_32x32x16_bf16(aw[dy * 3 + dx][kh], bfr, acc, 0, 0, 0);
                }
            }
        const int px = tb + r31;
        const int gx = x0 + px;
        if (px < 126 && gx < 1024) {
            #pragma unroll
            for (int g = 0; g < 4; ++g) {
                f32x4 v;
                #pragma unroll
                for (int e = 0; e < 4; ++e) {
                    float f = acc[g * 4 + e] + bb[g][e];
                    v[e] = f >= 0.f ? f : 0.01f * f;
                }
                *(f32x4*)&out[(size_t)((gy << 10) + gx) * 32 + g * 8 + h * 4] = v;
            }
        }
    };

    // prologue: X rows -2,-1,0
    stage(-2); stage(-1); stage(0);
    __syncthreads();

    // main: 19 iterations, one barrier each
    for (int t = 0; t <= 18; ++t) {
        if (t <= 16) stage(t + 1);
        if (isC1) { if (t <= 17) conv1_row(t - 1); }
        else      { if (t >= 3)  conv2_row(t - 3); }
        __syncthreads();
    }
}

extern "C" void kernel_launch(void* const* d_in, const int* in_sizes, int n_in,
                              void* d_out, int out_size, void* d_ws, size_t ws_size,
                              hipStream_t stream) {
    const float* Z1 = (const float*)d_in[0];
    const float* Z2 = (const float*)d_in[1];
    const float* Z3 = (const float*)d_in[2];
    const float* W1 = (const float*)d_in[3];
    const float* b1 = (const float*)d_in[4];
    const float* W2 = (const float*)d_in[5];
    const float* b2 = (const float*)d_in[6];

    // X (NHWC bf16, 67.1 MB) in ws; Bv2/Z1r in d_out-as-scratch (dead before fconv writes d_out)
    short* X   = (short*)d_ws;
    short* Bv2 = (short*)d_out;
    short* Z1r = Bv2 + 8388608;

    v_kernel  <<<1024, 256, 0, stream>>>(Z2, Z3, Bv2);
    z1r_kernel<<<64,   256, 0, stream>>>(Z1, Z1r);
    gemm_kernel<<<2048, 256, 0, stream>>>(Bv2, Z1r, X);
    fconv_kernel<<<dim3(9, 64), 512, 0, stream>>>(X, W1, b1, W2, b2, (float*)d_out);
}

// Round 10
// 150.151 us; speedup vs baseline: 1.0086x; 1.0086x over previous
//
#include <hip/hip_runtime.h>

typedef short  s16x4 __attribute__((ext_vector_type(4)));
typedef short  s16x8 __attribute__((ext_vector_type(8)));
typedef float  f32x4 __attribute__((ext_vector_type(4)));
typedef float  f32x16 __attribute__((ext_vector_type(16)));

__device__ __forceinline__ unsigned short f2b(float f) {
    unsigned u = __float_as_uint(f);
    u = u + 0x7FFFu + ((u >> 16) & 1u);   // RNE
    return (unsigned short)(u >> 16);
}

__device__ __forceinline__ void gload16(const void* g, void* l) {
    __builtin_amdgcn_global_load_lds((const __attribute__((address_space(1))) unsigned*)g,
                                     (__attribute__((address_space(3))) unsigned*)l,
                                     16, 0, 0);
}

// gemm slot swizzle (period 16)
__device__ __forceinline__ int swz(int x) { return (x ^ (x >> 2)) & 3; }
// fconv slot swizzle for 64B/px rows
__device__ __forceinline__ int f2s(int o) { return (o >> 1) & 3; }

// ---------- Bv2[(j*32+k)*256 + a*16+b] = sum_c Z2[b,j,c] * Z3[c,k,a]  (bf16) ----------
__global__ __launch_bounds__(256) void v_kernel(const float* __restrict__ Z2,
                                                const float* __restrict__ Z3,
                                                short* __restrict__ Bv2) {
    __shared__ float z3t[8192];   // [c][a][k]
    __shared__ float z2s[256];    // [b][c]
    const int tid = threadIdx.x, j = blockIdx.x;
    for (int t = tid; t < 8192; t += 256) {
        float v = Z3[t];                     // Z3[c,k,a] flat = c*512 + k*16 + a
        int c = t >> 9, k = (t >> 4) & 31, a = t & 15;
        z3t[c * 512 + a * 32 + k] = v;
    }
    z2s[tid] = Z2[(tid >> 4) * 16384 + j * 16 + (tid & 15)];
    __syncthreads();
    const int a = tid >> 4, b = tid & 15;
    float z2r[16];
    #pragma unroll
    for (int c = 0; c < 16; ++c) z2r[c] = z2s[b * 16 + c];
    float s[32];
    #pragma unroll
    for (int k = 0; k < 32; ++k) s[k] = 0.f;
    #pragma unroll
    for (int c = 0; c < 16; ++c) {
        #pragma unroll
        for (int k4 = 0; k4 < 8; ++k4) {
            f32x4 v = *(const f32x4*)&z3t[c * 512 + a * 32 + k4 * 4];
            #pragma unroll
            for (int r = 0; r < 4; ++r) s[k4 * 4 + r] += z2r[c] * v[r];
        }
    }
    #pragma unroll
    for (int k = 0; k < 32; ++k)
        Bv2[(size_t)(j * 32 + k) * 256 + tid] = (short)f2b(s[k]);
}

// ---------- Z1r[i*256 + a*16+b] = Z1[a,i,b]  (bf16) ----------
__global__ __launch_bounds__(256) void z1r_kernel(const float* __restrict__ Z1,
                                                  short* __restrict__ Z1r) {
    __shared__ float z1s[4096];
    const int tid = threadIdx.x, i0 = blockIdx.x * 16;
    #pragma unroll
    for (int a = 0; a < 16; ++a)
        z1s[a * 256 + tid] = Z1[a * 16384 + i0 * 16 + tid];
    __syncthreads();
    #pragma unroll
    for (int il = 0; il < 16; ++il)
        Z1r[(size_t)(i0 + il) * 256 + tid] =
            (short)f2b(z1s[(tid >> 4) * 256 + il * 16 + (tid & 15)]);
}

// ---------- X_nhwc[j][i][k] = sum_ab Bv2[(j*32+k)][ab] * Z1r[i][ab]  (bf16 MFMA) ----------
__global__ __launch_bounds__(256) void gemm_kernel(const short* __restrict__ Bv2,
                                                   const short* __restrict__ Z1r,
                                                   short* __restrict__ X) {
    __shared__ short sA[128 * 32];
    __shared__ short sB[128 * 32];
    const int tid = threadIdx.x;
    const int w = tid >> 6, lane = tid & 63, lane15 = lane & 15, q = lane >> 4;
    const int wm = w >> 1, wn = w & 1;
    const int bid = blockIdx.x;
    const int l = (bid & 7) * 256 + (bid >> 3);      // XCD-chunked swizzle
    const int n0 = (l >> 3) * 128, i0 = (l & 7) * 128;
    const int rs = lane >> 2, sp = lane & 3;
    const int scol = (sp ^ swz(rs)) << 3;
    const int fl = swz(lane15);

    f32x4 acc[4][4];
    #pragma unroll
    for (int a = 0; a < 4; ++a)
        #pragma unroll
        for (int b = 0; b < 4; ++b) acc[a][b] = (f32x4)0;

    for (int kk = 0; kk < 256; kk += 32) {
        gload16(&Bv2[(size_t)(n0 + w * 16 + rs) * 256 + kk + scol],       (char*)sA + w * 1024);
        gload16(&Bv2[(size_t)(n0 + (w + 4) * 16 + rs) * 256 + kk + scol], (char*)sA + (w + 4) * 1024);
        gload16(&Z1r[(size_t)(i0 + w * 16 + rs) * 256 + kk + scol],       (char*)sB + w * 1024);
        gload16(&Z1r[(size_t)(i0 + (w + 4) * 16 + rs) * 256 + kk + scol], (char*)sB + (w + 4) * 1024);
        __syncthreads();
        s16x8 af[4], bf[4];
        #pragma unroll
        for (int fm = 0; fm < 4; ++fm) {
            const int r = wm * 64 + fm * 16 + lane15;
            af[fm] = *(const s16x8*)&sA[r * 32 + ((q ^ fl) << 3)];
        }
        #pragma unroll
        for (int fn = 0; fn < 4; ++fn) {
            const int r = wn * 64 + fn * 16 + lane15;
            bf[fn] = *(const s16x8*)&sB[r * 32 + ((q ^ fl) << 3)];
        }
        #pragma unroll
        for (int fm = 0; fm < 4; ++fm)
            #pragma unroll
            for (int fn = 0; fn < 4; ++fn)
                acc[fm][fn] = __builtin_amdgcn_mfma_f32_16x16x32_bf16(af[fm], bf[fn], acc[fm][fn], 0, 0, 0);
        __syncthreads();
    }

    #pragma unroll
    for (int fm = 0; fm < 4; ++fm) {
        const int nbase = n0 + wm * 64 + fm * 16;
        const int j = nbase >> 5;
        const int k0 = (nbase & 31) + q * 4;
        #pragma unroll
        for (int fn = 0; fn < 4; ++fn) {
            const int i = i0 + wn * 64 + fn * 16 + lane15;
            s16x4 p;
            #pragma unroll
            for (int r = 0; r < 4; ++r) p[r] = (short)f2b(acc[fm][fn][r]);
            *(s16x4*)&X[(size_t)j * 32768 + i * 32 + k0] = p;
        }
    }
}

// ---------- fused conv1+leaky+conv2+leaky, NHWC, producer/consumer, 32x32x16 MFMA ----------
// 512 threads = 8 waves. Tile: 126 out px x 16 rows, grid 9x64.
// Waves 0-3: conv1 (y1 tiles base -1,31,63,95). Waves 4-7: conv2 (out tiles 0,32,64,96).
// X ring: FIVE rows x 130 px; y1 ring: 4 rows x 130 px.
// Per iter t: stage X row t+2 (2-AHEAD) || conv1 y1 row t-1 || conv2 out row t-3;
// barrier = s_waitcnt vmcnt(1) lgkmcnt(0) + s_barrier (T4: never drain vmcnt to 0 in-loop).
// vmcnt(1): only this iter's newest stage-load may remain in flight -> loads issued at
// iter t are complete by the barrier entering iter t+2, when conv1 first reads them.
// Ledger: X slot(rho)=rho%5; stage t+2 vs conv1 reads {t-2..t} -> t+2 == t-3 (mod 5), disjoint;
// row rho last read iter rho+2, re-staged iter rho+3. y1 slot (t+3)&3 vs reads {t,t+1,t+2}&3.
#define XWN 130
#define XRN (XWN * 32)          // shorts per ring row (8320 B)
#define PIPE_BARRIER() do { \
    asm volatile("s_waitcnt vmcnt(1) lgkmcnt(0)" ::: "memory"); \
    __builtin_amdgcn_s_barrier(); \
    asm volatile("" ::: "memory"); \
} while (0)
__global__ __launch_bounds__(512) void fconv_kernel(const short* __restrict__ in,
                                                    const float* __restrict__ W1,
                                                    const float* __restrict__ b1,
                                                    const float* __restrict__ W2,
                                                    const float* __restrict__ b2,
                                                    float* __restrict__ out) {
    __shared__ short xr[5 * XRN];   // 41600 B
    __shared__ short yr[4 * XRN];   // 33280 B
    const int tid = threadIdx.x;
    const int w = tid >> 6, lane = tid & 63, r31 = lane & 31, h = lane >> 5;
    const int bx = blockIdx.x, by = blockIdx.y;
    const int x0 = bx * 126, y0 = by * 16;
    const bool isC1 = (w < 4);
    const int tb = isC1 ? (w * 32 - 1) : ((w - 4) * 32);   // y1-tile base (rel px) / out-tile base

    // A-frags for 32x32x16: A[o][c], o = lane&31, c = kh*16 + h*8 + e  (72 VGPR/wave)
    s16x8 aw[9][2];
    {
        const float* Ws = isC1 ? W1 : W2;
        #pragma unroll
        for (int t = 0; t < 9; ++t)
            #pragma unroll
            for (int kh = 0; kh < 2; ++kh) {
                const int c0 = kh * 16 + h * 8;
                s16x8 a;
                #pragma unroll
                for (int e = 0; e < 8; ++e)
                    a[e] = (short)f2b(Ws[(r31 * 32 + c0 + e) * 9 + t]);
                aw[t][kh] = a;
            }
    }
    // bias per C/D reg: o(reg) = (reg&3) + 8*(reg>>2) + 4*h
    f32x4 bb[4];
    {
        const float* bs = isC1 ? b1 : b2;
        #pragma unroll
        for (int g = 0; g < 4; ++g) bb[g] = *(const f32x4*)&bs[g * 8 + h * 4];
    }

    // persistent zeros for x-halo at image edges (stage skips OOB gx).
    // Barrier REQUIRED before any gload16 lands in xr (round-5 race lesson).
    if (bx == 0 || bx == 8) {
        s16x8* p = (s16x8*)xr;
        for (int i = tid; i < 5 * XWN * 4; i += 512) p[i] = (s16x8)0;
        __syncthreads();
    }

    auto stage = [&](int rho) {                      // X image row y0+rho -> slot (rho+5)%5
        const int gy = y0 + rho;
        char* base = (char*)&xr[((rho + 5) % 5) * XRN];
        if ((unsigned)gy < 1024u) {
            // 520 16B-slots over 512 threads (+8-thread tail)
            {
                const int ox = tid >> 2, u = tid & 3;
                const int gx = x0 - 2 + ox;
                if ((unsigned)gx < 1024u)
                    gload16(&in[(size_t)((gy << 10) + gx) * 32 + ((u ^ f2s(ox)) << 3)],
                            base + (w * 64) * 16);
            }
            {
                const int idx = 512 + tid;
                if (idx < XWN * 4) {                 // tid < 8 (wave 0 tail)
                    const int ox = idx >> 2, u = idx & 3;
                    const int gx = x0 - 2 + ox;
                    if ((unsigned)gx < 1024u)
                        gload16(&in[(size_t)((gy << 10) + gx) * 32 + ((u ^ f2s(ox)) << 3)],
                                base + 512 * 16);
                }
            }
        } else {
            s16x8* b8 = (s16x8*)base;
            for (int i = tid; i < XWN * 4; i += 512) b8[i] = (s16x8)0;
        }
    };

    auto conv1_row = [&](int ry) {                   // y1 image row y0+ry -> slot (ry+4)&3
        const int gy1 = y0 + ry;
        const int ysl = ((ry + 4) & 3) * XRN;
        if ((unsigned)gy1 < 1024u) {
            int xs[3];
            #pragma unroll
            for (int dy = 0; dy < 3; ++dy) xs[dy] = ((ry - 1 + dy + 5) % 5) * XRN;
            f32x16 acc = (f32x16)0;
            __builtin_amdgcn_s_setprio(1);
            #pragma unroll
            for (int dy = 0; dy < 3; ++dy)
                #pragma unroll
                for (int dx = 0; dx < 3; ++dx) {
                    const int ox = tb + r31 + dx + 1;          // X offset 0..129
                    const int fo = f2s(ox);
                    #pragma unroll
                    for (int kh = 0; kh < 2; ++kh) {
                        const s16x8 bfr = *(const s16x8*)&xr[xs[dy] + ox * 32 + (((kh * 2 + h) ^ fo) << 3)];
                        acc = __builtin_amdgcn_mfma_f32_32x32x16_bf16(aw[dy * 3 + dx][kh], bfr, acc, 0, 0, 0);
                    }
                }
            __builtin_amdgcn_s_setprio(0);
            const int p = tb + r31;                  // y1 rel px, -1..126
            const int oy = p + 1;                    // LDS offset 0..127
            const int gx1 = x0 + p;
            const bool valid = (unsigned)gx1 < 1024u;    // conv2 zero-pads y1 at image edge
            const int fo = f2s(oy);
            #pragma unroll
            for (int g = 0; g < 4; ++g) {
                s16x4 pk;
                #pragma unroll
                for (int e = 0; e < 4; ++e) {
                    float f = acc[g * 4 + e] + bb[g][e];
                    f = f >= 0.f ? f : 0.01f * f;
                    pk[e] = valid ? (short)f2b(f) : (short)0;
                }
                *(s16x4*)&yr[ysl + oy * 32 + ((g ^ fo) << 3) + h * 4] = pk;
            }
        } else {                                     // conv2 zero-padding row (waves 0-3 only)
            s16x8* b8 = (s16x8*)&yr[ysl];
            for (int i = tid; i < XWN * 4; i += 256) b8[i] = (s16x8)0;
        }
    };

    auto conv2_row = [&](int ro) {                   // out image row y0+ro (always valid)
        const int gy = y0 + ro;
        int ys[3];
        #pragma unroll
        for (int dy = 0; dy < 3; ++dy) ys[dy] = ((ro - 1 + dy + 4) & 3) * XRN;
        f32x16 acc = (f32x16)0;
        __builtin_amdgcn_s_setprio(1);
        #pragma unroll
        for (int dy = 0; dy < 3; ++dy)
            #pragma unroll
            for (int dx = 0; dx < 3; ++dx) {
                const int oy = tb + r31 + dx;                  // y1 offset 0..129
                const int fo = f2s(oy);
                #pragma unroll
                for (int kh = 0; kh < 2; ++kh) {
                    const s16x8 bfr = *(const s16x8*)&yr[ys[dy] + oy * 32 + (((kh * 2 + h) ^ fo) << 3)];
                    acc = __builtin_amdgcn_mfma_f32_32x32x16_bf16(aw[dy * 3 + dx][kh], bfr, acc, 0, 0, 0);
                }
            }
        __builtin_amdgcn_s_setprio(0);
        const int px = tb + r31;
        const int gx = x0 + px;
        if (px < 126 && gx < 1024) {
            #pragma unroll
            for (int g = 0; g < 4; ++g) {
                f32x4 v;
                #pragma unroll
                for (int e = 0; e < 4; ++e) {
                    float f = acc[g * 4 + e] + bb[g][e];
                    v[e] = f >= 0.f ? f : 0.01f * f;
                }
                *(f32x4*)&out[(size_t)((gy << 10) + gx) * 32 + g * 8 + h * 4] = v;
            }
        }
    };

    // prologue: X rows -2..1 (full drain once)
    stage(-2); stage(-1); stage(0); stage(1);
    __syncthreads();

    // main: 19 iterations, counted-vmcnt barrier each
    for (int t = 0; t <= 18; ++t) {
        if (t <= 15) stage(t + 2);
        if (isC1) { if (t <= 17) conv1_row(t - 1); }
        else      { if (t >= 3)  conv2_row(t - 3); }
        PIPE_BARRIER();
    }
}

extern "C" void kernel_launch(void* const* d_in, const int* in_sizes, int n_in,
                              void* d_out, int out_size, void* d_ws, size_t ws_size,
                              hipStream_t stream) {
    const float* Z1 = (const float*)d_in[0];
    const float* Z2 = (const float*)d_in[1];
    const float* Z3 = (const float*)d_in[2];
    const float* W1 = (const float*)d_in[3];
    const float* b1 = (const float*)d_in[4];
    const float* W2 = (const float*)d_in[5];
    const float* b2 = (const float*)d_in[6];

    // X (NHWC bf16, 67.1 MB) in ws; Bv2/Z1r in d_out-as-scratch (dead before fconv writes d_out)
    short* X   = (short*)d_ws;
    short* Bv2 = (short*)d_out;
    short* Z1r = Bv2 + 8388608;

    v_kernel  <<<1024, 256, 0, stream>>>(Z2, Z3, Bv2);
    z1r_kernel<<<64,   256, 0, stream>>>(Z1, Z1r);
    gemm_kernel<<<2048, 256, 0, stream>>>(Bv2, Z1r, X);
    fconv_kernel<<<dim3(9, 64), 512, 0, stream>>>(X, W1, b1, W2, b2, (float*)d_out);
}